// Round 27
// baseline (154.336 us; speedup 1.0000x reference)
//
#include <hip/hip_runtime.h>

#define SQ 2048
#define DH 128
#define KVB 64
#define BHN 32
#define ELEMS ((size_t)BHN * SQ * DH)   // 8388608 per tensor

typedef __bf16 bf16x8 __attribute__((ext_vector_type(8)));
typedef float f32x16 __attribute__((ext_vector_type(16)));
typedef unsigned uint2v __attribute__((ext_vector_type(2)));

__device__ __forceinline__ f32x16 mfma32(bf16x8 a, bf16x8 b, f32x16 c){
  return __builtin_amdgcn_mfma_f32_32x32x16_bf16(a, b, c, 0, 0, 0);
}

#define EXP2 __builtin_amdgcn_exp2f

__device__ __forceinline__ unsigned short f2bf(float f){
  unsigned u = __builtin_bit_cast(unsigned, f);
  u += 0x7fffu + ((u >> 16) & 1u);
  return (unsigned short)(u >> 16);
}
__device__ __forceinline__ unsigned packbf(float a, float b){
  return (unsigned)f2bf(a) | ((unsigned)f2bf(b) << 16);
}
// HW packed f32->bf16 pair
__device__ __forceinline__ unsigned cvtpk(float a, float b){
  unsigned w;
  asm("v_cvt_pk_bf16_f32 %0, %1, %2" : "=v"(w) : "v"(a), "v"(b));
  return w;
}

// HW cross-half exchange: x = {a[0:31], b[0:31]}, y = {a[32:63], b[32:63]}
#if __has_builtin(__builtin_amdgcn_permlane32_swap)
__device__ __forceinline__ void swap32p(unsigned a, unsigned b, unsigned &x, unsigned &y){
  uint2v r = __builtin_amdgcn_permlane32_swap(a, b, false, false);
  x = r[0]; y = r[1];
}
#else
__device__ __forceinline__ void swap32p(unsigned a, unsigned b, unsigned &x, unsigned &y){
  x = a; y = b;
  asm volatile("" : "+v"(x), "+v"(y));
  asm("v_permlane32_swap_b32 %0, %1" : "+v"(x), "+v"(y));
}
#endif
__device__ __forceinline__ float halfmax(float t){
  unsigned u = __builtin_bit_cast(unsigned, t), x, y;
  swap32p(u, u, x, y);
  return fmaxf(__builtin_bit_cast(float, x), __builtin_bit_cast(float, y));
}
__device__ __forceinline__ float halfadd(float t){
  unsigned u = __builtin_bit_cast(unsigned, t), x, y;
  swap32p(u, u, x, y);
  return __builtin_bit_cast(float, x) + __builtin_bit_cast(float, y);
}

// emulated version (fallback kernel only)
__device__ __forceinline__ void swap32(unsigned a, unsigned b, bool h, unsigned &x, unsigned &y){
  unsigned sb = __shfl_xor(b, 32);
  unsigned sa = __shfl_xor(a, 32);
  x = h ? sb : a;
  y = h ? b : sa;
}

__device__ __forceinline__ bf16x8 mkfrag(unsigned w0, unsigned w1, unsigned w2, unsigned w3){
  uint4 t; t.x = w0; t.y = w1; t.z = w2; t.w = w3;
  return __builtin_bit_cast(bf16x8, t);
}

// ---- fused preprocess: K fp32->bf16 (blocks 0..1023) + V transpose (1024..3071) ----
__global__ __launch_bounds__(256, 4)
void convkvt(const float* __restrict__ K, const float* __restrict__ V,
             unsigned short* __restrict__ Kb, unsigned short* __restrict__ Vt){
  if (blockIdx.x < 1024){
    const size_t g = (size_t)blockIdx.x * 256 + threadIdx.x;
    #pragma unroll
    for (int i = 0; i < 4; ++i){
      size_t e = (g + (size_t)i * 262144) * 8;
      float4 a = *(const float4*)(K + e);
      float4 b = *(const float4*)(K + e + 4);
      uint4 o;
      o.x = packbf(a.x, a.y); o.y = packbf(a.z, a.w);
      o.z = packbf(b.x, b.y); o.w = packbf(b.z, b.w);
      *(uint4*)(Kb + e) = o;
    }
  } else {
    __shared__ unsigned short T[64][65];
    const int bidx = blockIdx.x - 1024;     // ((bh*32)+kt)*2+dt
    const int dt = bidx & 1;
    const int kt = (bidx >> 1) & 31;
    const int bh = bidx >> 6;
    const float* src = V + (size_t)bh*SQ*DH + (size_t)kt*64*DH + dt*64;
    unsigned short* dst = Vt + (size_t)bh*DH*SQ + (size_t)dt*64*SQ + kt*64;
    const int t = threadIdx.x;
    const int c4 = (t & 15) * 4;
    const int r0 = t >> 4;
    #pragma unroll
    for (int i = 0; i < 4; ++i){
      int r = r0 + i*16;
      float4 f = *(const float4*)(src + (size_t)r*DH + c4);
      T[r][c4+0] = f2bf(f.x); T[r][c4+1] = f2bf(f.y);
      T[r][c4+2] = f2bf(f.z); T[r][c4+3] = f2bf(f.w);
    }
    __syncthreads();
    #pragma unroll
    for (int i = 0; i < 4; ++i){
      int d = r0 + i*16;
      ushort4 w;
      w.x = T[c4+0][d]; w.y = T[c4+1][d]; w.z = T[c4+2][d]; w.w = T[c4+3][d];
      *(ushort4*)(dst + (size_t)d*SQ + c4) = w;
    }
  }
}

// ---- main kernel: NO LDS staging, NO main-loop barriers.
// Each wave streams its own K/V fragments from global (L1/L2-resident bf16).
__global__ __launch_bounds__(512, 2)
void attn_fwd_reg(const float* __restrict__ Q,
                  const unsigned short* __restrict__ Kbg,
                  const unsigned short* __restrict__ Vtg,
                  float* __restrict__ O)
{
  __shared__ float SF[8704];   // 34.8KB: parity-merge scratch only

  const int tid  = threadIdx.x;
  const int lane = tid & 63;
  const int wid  = tid >> 6;
  const int rg   = wid & 3;
  const int par  = wid >> 2;
  const int col  = lane & 31;
  const int hi   = lane >> 5;

  const int b   = blockIdx.x;
  const int xcd = b & 7;
  const int seq = b >> 3;
  const int bh4 = seq & 3;
  const int j   = seq >> 2;
  const int bh  = xcd + 8*bh4;

  const size_t base = (size_t)bh * SQ * DH;
  const float* Qg = Q + base;
  const unsigned short* Kb = Kbg + base;
  const unsigned short* Vt = Vtg + base;     // [128][2048]
  float* Og = O + base;

  const float SC = 0.08838834764831845f * 1.4426950408889634f;

  const int krow_l = par*32 + col;           // K row within tile

  #pragma unroll 1
  for (int ph = 0; ph < 2; ++ph){
    const int qt = ph ? j : (15 - j);
    const int nt = 2*qt + 2;          // even, >= 2
    const int Q0 = qt*128 + rg*32;
    const int qg = Q0 + col;

    // Q fragments, softmax scale folded in
    bf16x8 qf[8];
    #pragma unroll
    for (int dc = 0; dc < 8; ++dc){
      const float* src = Qg + (size_t)qg*DH + dc*16 + hi*8;
      float4 f0 = *(const float4*)(src);
      float4 f1 = *(const float4*)(src + 4);
      uint4 tq;
      tq.x = packbf(f0.x*SC, f0.y*SC); tq.y = packbf(f0.z*SC, f0.w*SC);
      tq.z = packbf(f1.x*SC, f1.y*SC); tq.w = packbf(f1.z*SC, f1.w*SC);
      qf[dc] = __builtin_bit_cast(bf16x8, tq);
    }

    f32x16 o0 = {}, o1 = {}, o2 = {}, o3 = {};
    float m = -1e30f, lsum = 0.f;

    uint4 kfA[8], kfB[8];   // static-indexed K double buffer (rule #20)

    // prologue: tile-0 K fragment (if this wave has any valid work at t=0)
    if (krow_l <= Q0 + 31){
      const unsigned short* p = Kb + (size_t)krow_l*DH + hi*8;
      #pragma unroll
      for (int dc = 0; dc < 8; ++dc) kfA[dc] = *(const uint4*)(p + dc*16);
    }

    // one tile-step: prefetch K(t+1) into knext, then V(t)+QK(t)+softmax+PV(t)
    auto STEP = [&](int t, uint4 (&kcur)[8], uint4 (&knext)[8]){
      const int kvb = t * KVB;
      const int myk = kvb + krow_l;

      if (t + 1 < nt && (kvb + KVB + krow_l) <= qg + (31 - col) + 0){
        // prefetch condition == next tile valid for this wave: kvb+KVB+par*32 <= Q0+31
      }
      if (t + 1 < nt && (kvb + KVB + par*32) <= Q0 + 31){
        const unsigned short* p = Kb + (size_t)(kvb + KVB + krow_l)*DH + hi*8;
        #pragma unroll
        for (int dc = 0; dc < 8; ++dc) knext[dc] = *(const uint4*)(p + dc*16);
      }

      if (kvb + par*32 <= Q0 + 31){
        // V fragment loads issued BEFORE QK: latency hides under QK+softmax
        uint4 vfr[8];
        #pragma unroll
        for (int cc = 0; cc < 2; ++cc){
          #pragma unroll
          for (int db = 0; db < 4; ++db){
            vfr[cc*4+db] = *(const uint4*)(Vt + (size_t)(db*32 + col)*SQ
                                           + kvb + par*32 + cc*16 + hi*8);
          }
        }

        // QK^T (swapped): S^T[k][q], k = this wave's 32-row chunk
        f32x16 s0 = {};
        #pragma unroll
        for (int dc = 0; dc < 8; ++dc)
          s0 = mfma32(__builtin_bit_cast(bf16x8, kcur[dc]), qf[dc], s0);

        if (myk - col + 31 > Q0){   // kvb+par*32+31 > Q0: diagonal tile
          #pragma unroll
          for (int r = 0; r < 16; ++r){
            int kl = (r & 3) + 8*(r >> 2) + 4*hi;
            if (kvb + par*32 + kl > qg) s0[r] = -1e30f;
          }
        }

        // tree max + HW cross-half max
        float p0 = fmaxf(s0[0],  s0[1]),  p1 = fmaxf(s0[2],  s0[3]);
        float p2 = fmaxf(s0[4],  s0[5]),  p3 = fmaxf(s0[6],  s0[7]);
        float p4 = fmaxf(s0[8],  s0[9]),  p5 = fmaxf(s0[10], s0[11]);
        float p6 = fmaxf(s0[12], s0[13]), p7 = fmaxf(s0[14], s0[15]);
        float tmax = halfmax(fmaxf(fmaxf(fmaxf(p0,p1), fmaxf(p2,p3)),
                                   fmaxf(fmaxf(p4,p5), fmaxf(p6,p7))));
        if (!__all(tmax <= m + 8.0f)){      // T13 defer-max
          float mnew  = fmaxf(m, tmax);
          float alpha = EXP2(m - mnew);
          m = mnew;
          lsum *= alpha;
          o0 *= alpha; o1 *= alpha; o2 *= alpha; o3 *= alpha;
        }

        float e0  = EXP2(s0[0]  - m), e1  = EXP2(s0[1]  - m);
        float e2  = EXP2(s0[2]  - m), e3  = EXP2(s0[3]  - m);
        float e4  = EXP2(s0[4]  - m), e5  = EXP2(s0[5]  - m);
        float e6  = EXP2(s0[6]  - m), e7  = EXP2(s0[7]  - m);
        float e8  = EXP2(s0[8]  - m), e9  = EXP2(s0[9]  - m);
        float e10 = EXP2(s0[10] - m), e11 = EXP2(s0[11] - m);
        float e12 = EXP2(s0[12] - m), e13 = EXP2(s0[13] - m);
        float e14 = EXP2(s0[14] - m), e15 = EXP2(s0[15] - m);
        lsum += (((e0+e1)+(e2+e3)) + ((e4+e5)+(e6+e7)))
              + (((e8+e9)+(e10+e11)) + ((e12+e13)+(e14+e15)));

        unsigned ua0 = cvtpk(e0,  e1),  ua1 = cvtpk(e2,  e3);
        unsigned ua2 = cvtpk(e4,  e5),  ua3 = cvtpk(e6,  e7);
        unsigned ua4 = cvtpk(e8,  e9),  ua5 = cvtpk(e10, e11);
        unsigned ua6 = cvtpk(e12, e13), ua7 = cvtpk(e14, e15);
        unsigned w0, w1, w2, w3;
        bf16x8 pf[2];
        swap32p(ua0, ua2, w0, w2); swap32p(ua1, ua3, w1, w3); pf[0] = mkfrag(w0,w1,w2,w3);
        swap32p(ua4, ua6, w0, w2); swap32p(ua5, ua7, w1, w3); pf[1] = mkfrag(w0,w1,w2,w3);

        // PV
        #pragma unroll
        for (int cc = 0; cc < 2; ++cc){
          #pragma unroll
          for (int db = 0; db < 4; ++db){
            f32x16& oo = (db==0)?o0:(db==1)?o1:(db==2)?o2:o3;
            oo = mfma32(__builtin_bit_cast(bf16x8, vfr[cc*4+db]), pf[cc], oo);
          }
        }
      }
    };

    #pragma unroll 1
    for (int t = 0; t < nt; t += 2){
      STEP(t,     kfA, kfB);
      STEP(t + 1, kfB, kfA);
    }

    // ---- epilogue: combine hi-halves, then parity merge via LDS ----
    lsum = halfadd(lsum);

    float a0 = 1.f, a1 = 0.f, inv = 0.f;
    #pragma unroll 1
    for (int round = 0; round < 2; ++round){
      const f32x16& pa = round ? o2 : o0;
      const f32x16& pb = round ? o3 : o1;
      if (par == 1){
        #pragma unroll
        for (int i2 = 0; i2 < 16; ++i2){
          SF[rg*2048 + i2*64 + lane]      = pa[i2];
          SF[rg*2048 + (16+i2)*64 + lane] = pb[i2];
        }
        if (round == 0){
          SF[8192 + rg*64 + lane] = m;
          SF[8448 + rg*64 + lane] = lsum;
        }
      }
      __syncthreads();
      if (par == 0){
        if (round == 0){
          float m1 = SF[8192 + rg*64 + lane];
          float l1 = SF[8448 + rg*64 + lane];
          float ms = fmaxf(m, m1);
          a0 = EXP2(m - ms);
          a1 = EXP2(m1 - ms);
          float ls = lsum*a0 + l1*a1;
          inv = 1.0f / ls;
        }
        #pragma unroll
        for (int dbi = 0; dbi < 2; ++dbi){
          const f32x16& oo = round ? (dbi ? o3 : o2) : (dbi ? o1 : o0);
          const int db = round*2 + dbi;
          #pragma unroll
          for (int rg2 = 0; rg2 < 4; ++rg2){
            float4 w;
            w.x = (oo[rg2*4+0]*a0 + SF[rg*2048 + (dbi*16 + rg2*4+0)*64 + lane]*a1) * inv;
            w.y = (oo[rg2*4+1]*a0 + SF[rg*2048 + (dbi*16 + rg2*4+1)*64 + lane]*a1) * inv;
            w.z = (oo[rg2*4+2]*a0 + SF[rg*2048 + (dbi*16 + rg2*4+2)*64 + lane]*a1) * inv;
            w.w = (oo[rg2*4+3]*a0 + SF[rg*2048 + (dbi*16 + rg2*4+3)*64 + lane]*a1) * inv;
            *(float4*)(Og + (size_t)qg*DH + db*32 + rg2*8 + hi*4) = w;
          }
        }
      }
      __syncthreads();
    }
  }
}

// ---- fallback (ws too small): reg-staged fp32 LDS path (R18-verified) ----
__global__ __launch_bounds__(512, 2)
void attn_fwd_fb(const float* __restrict__ Q,
                 const float* __restrict__ Kf,
                 const float* __restrict__ Vf,
                 float* __restrict__ O)
{
  __shared__ __align__(16) unsigned char smem[65536];
  float* SF = (float*)smem;
  const int tid  = threadIdx.x;
  const int lane = tid & 63;
  const int wid  = tid >> 6;
  const int rg   = wid & 3;
  const int par  = wid >> 2;
  const int col  = lane & 31;
  const int hi   = lane >> 5;
  const int i4   = lane & 3;
  const int d0   = (lane >> 2)*8;
  const int b   = blockIdx.x;
  const int xcd = b & 7;
  const int seq = b >> 3;
  const int bh4 = seq & 3;
  const int j   = seq >> 2;
  const int bh  = xcd + 8*bh4;
  const size_t base = (size_t)bh * SQ * DH;
  const float* Qg = Q + base;
  const float* Kg = Kf + base;
  const float* Vg = Vf + base;
  float* Og = O + base;
  const float SC = 0.08838834764831845f * 1.4426950408889634f;
  float4 kr[4], vr[4];
  auto LOADT = [&](int kvb){
    #pragma unroll
    for (int i2 = 0; i2 < 2; ++i2){
      int c = i2*512 + tid, r = c >> 4, dc = c & 15;
      const float* src = Kg + (size_t)(kvb + r)*DH + dc*8;
      kr[2*i2]   = *(const float4*)(src);
      kr[2*i2+1] = *(const float4*)(src + 4);
    }
    #pragma unroll
    for (int it = 0; it < 2; ++it){
      int row = wid*8 + it*4 + i4;
      const float* src = Vg + (size_t)(kvb + row)*DH + d0;
      vr[2*it]   = *(const float4*)(src);
      vr[2*it+1] = *(const float4*)(src + 4);
    }
  };
  auto STORET = [&](int bsel){
    const int bboff = bsel * 32768;
    #pragma unroll
    for (int i2 = 0; i2 < 2; ++i2){
      int c = i2*512 + tid, r = c >> 4, dc = c & 15;
      uint4 kv;
      kv.x = packbf(kr[2*i2].x,   kr[2*i2].y);
      kv.y = packbf(kr[2*i2].z,   kr[2*i2].w);
      kv.z = packbf(kr[2*i2+1].x, kr[2*i2+1].y);
      kv.w = packbf(kr[2*i2+1].z, kr[2*i2+1].w);
      *(uint4*)&smem[bboff + r*256 + ((dc*16) ^ ((r & 7) << 4))] = kv;
    }
    #pragma unroll
    for (int it = 0; it < 2; ++it){
      int r0 = wid*8 + it*4;
      unsigned M0 = packbf(vr[2*it].x,   vr[2*it].y);
      unsigned M1 = packbf(vr[2*it].z,   vr[2*it].w);
      unsigned M2 = packbf(vr[2*it+1].x, vr[2*it+1].y);
      unsigned M3 = packbf(vr[2*it+1].z, vr[2*it+1].w);
      unsigned t0=__shfl_xor(M1,1), t1=__shfl_xor(M0,1), t2=__shfl_xor(M3,1), t3=__shfl_xor(M2,1);
      bool ob1 = i4 & 1;
      unsigned N0 = ob1 ? t0 : M0;
      unsigned N1 = ob1 ? M1 : t1;
      unsigned N2 = ob1 ? t2 : M2;
      unsigned N3 = ob1 ? M3 : t3;
      unsigned u0s=__shfl_xor(N2,2), u1s=__shfl_xor(N3,2), u2s=__shfl_xor(N0,2), u3s=__shfl_xor(N1,2);
      bool ob2 = i4 & 2;
      unsigned F0 = ob2 ? u0s : N0;
      unsigned F1 = ob2 ? u1s : N1;
      unsigned F2 = ob2 ? N2 : u2s;
      unsigned F3 = ob2 ? N3 : u3s;
      int d = d0 + 2*i4;
      unsigned lo0 = (F0 & 0xffffu) | (F1 << 16);
      unsigned lo1 = (F2 & 0xffffu) | (F3 << 16);
      unsigned hi0 = (F0 >> 16) | (F1 & 0xffff0000u);
      unsigned hi1 = (F2 >> 16) | (F3 & 0xffff0000u);
      int cb = r0*2;
      int sA = ((d >> 1) & 7) << 4;
      *(uint2*)&smem[bboff + 16384 + d*128     + (cb ^ sA)] = make_uint2(lo0, lo1);
      *(uint2*)&smem[bboff + 16384 + (d+1)*128 + (cb ^ sA)] = make_uint2(hi0, hi1);
    }
  };
  #pragma unroll 1
  for (int ph = 0; ph < 2; ++ph){
    const int qt = ph ? j : (15 - j);
    const int nt = 2*qt + 2;
    const int Q0 = qt*128 + rg*32;
    const int qg = Q0 + col;
    bf16x8 qf[8];
    #pragma unroll
    for (int dc = 0; dc < 8; ++dc){
      const float* src = Qg + (size_t)qg*DH + dc*16 + hi*8;
      float4 f0 = *(const float4*)(src);
      float4 f1 = *(const float4*)(src + 4);
      uint4 tq;
      tq.x = packbf(f0.x*SC, f0.y*SC); tq.y = packbf(f0.z*SC, f0.w*SC);
      tq.z = packbf(f1.x*SC, f1.y*SC); tq.w = packbf(f1.z*SC, f1.w*SC);
      qf[dc] = __builtin_bit_cast(bf16x8, tq);
    }
    f32x16 o0 = {}, o1 = {}, o2 = {}, o3 = {};
    float m = -1e30f, lsum = 0.f;
    LOADT(0);
    STORET(0);
    __syncthreads();
    #pragma unroll 1
    for (int t = 0; t < nt; ++t){
      const int kvb = t * KVB;
      const int bboff = (t & 1) * 32768;
      const int myk = kvb + par*32;
      if (t + 1 < nt) LOADT(kvb + KVB);
      if (myk <= Q0 + 31){
        f32x16 s0 = {};
        const int krow = par*32 + col;
        #pragma unroll
        for (int dc = 0; dc < 8; ++dc){
          uint4 rk = *(const uint4*)&smem[bboff + krow*256 + ((dc*32 + hi*16) ^ ((krow & 7) << 4))];
          s0 = mfma32(__builtin_bit_cast(bf16x8, rk), qf[dc], s0);
        }
        if (myk + 31 > Q0){
          #pragma unroll
          for (int r = 0; r < 16; ++r){
            int kl = (r & 3) + 8*(r >> 2) + 4*hi;
            if (myk + kl > qg) s0[r] = -1e30f;
          }
        }
        float tmax = -1e30f;
        #pragma unroll
        for (int r = 0; r < 16; ++r) tmax = fmaxf(tmax, s0[r]);
        tmax = fmaxf(tmax, __shfl_xor(tmax, 32));
        if (!__all(tmax <= m + 8.0f)){
          float mnew  = fmaxf(m, tmax);
          float alpha = EXP2(m - mnew);
          m = mnew;
          lsum *= alpha;
          o0 *= alpha; o1 *= alpha; o2 *= alpha; o3 *= alpha;
        }
        float ps = 0.f;
        #pragma unroll
        for (int r = 0; r < 16; ++r){ float e = EXP2(s0[r] - m); s0[r] = e; ps += e; }
        lsum += ps;
        unsigned ua0 = packbf(s0[0],  s0[1]),  ua1 = packbf(s0[2],  s0[3]);
        unsigned ua2 = packbf(s0[4],  s0[5]),  ua3 = packbf(s0[6],  s0[7]);
        unsigned ua4 = packbf(s0[8],  s0[9]),  ua5 = packbf(s0[10], s0[11]);
        unsigned ua6 = packbf(s0[12], s0[13]), ua7 = packbf(s0[14], s0[15]);
        bool h = (bool)hi;
        unsigned w0, w1, w2, w3;
        bf16x8 pf[2];
        swap32(ua0, ua2, h, w0, w2); swap32(ua1, ua3, h, w1, w3); pf[0] = mkfrag(w0,w1,w2,w3);
        swap32(ua4, ua6, h, w0, w2); swap32(ua5, ua7, h, w1, w3); pf[1] = mkfrag(w0,w1,w2,w3);
        #pragma unroll
        for (int cc = 0; cc < 2; ++cc){
          #pragma unroll
          for (int db = 0; db < 4; ++db){
            int rowd = db*32 + col;
            uint4 rv = *(const uint4*)&smem[bboff + 16384 + rowd*128 + ((par*64 + cc*32 + hi*16) ^ (((rowd >> 1) & 7) << 4))];
            f32x16& oo = (db==0)?o0:(db==1)?o1:(db==2)?o2:o3;
            oo = mfma32(__builtin_bit_cast(bf16x8, rv), pf[cc], oo);
          }
        }
      }
      if (t + 1 < nt) STORET((t + 1) & 1);
      __syncthreads();
    }
    lsum += __shfl_xor(lsum, 32);
    float a0 = 1.f, a1 = 0.f, inv = 0.f;
    #pragma unroll 1
    for (int round = 0; round < 2; ++round){
      const f32x16& pa = round ? o2 : o0;
      const f32x16& pb = round ? o3 : o1;
      if (par == 1){
        #pragma unroll
        for (int i2 = 0; i2 < 16; ++i2){
          SF[rg*2048 + i2*64 + lane]      = pa[i2];
          SF[rg*2048 + (16+i2)*64 + lane] = pb[i2];
        }
        if (round == 0){
          SF[8192 + rg*64 + lane] = m;
          SF[8448 + rg*64 + lane] = lsum;
        }
      }
      __syncthreads();
      if (par == 0){
        if (round == 0){
          float m1 = SF[8192 + rg*64 + lane];
          float l1 = SF[8448 + rg*64 + lane];
          float ms = fmaxf(m, m1);
          a0 = EXP2(m - ms);
          a1 = EXP2(m1 - ms);
          float ls = lsum*a0 + l1*a1;
          inv = 1.0f / ls;
        }
        #pragma unroll
        for (int dbi = 0; dbi < 2; ++dbi){
          const f32x16& oo = round ? (dbi ? o3 : o2) : (dbi ? o1 : o0);
          const int db = round*2 + dbi;
          #pragma unroll
          for (int rg2 = 0; rg2 < 4; ++rg2){
            float4 w;
            w.x = (oo[rg2*4+0]*a0 + SF[rg*2048 + (dbi*16 + rg2*4+0)*64 + lane]*a1) * inv;
            w.y = (oo[rg2*4+1]*a0 + SF[rg*2048 + (dbi*16 + rg2*4+1)*64 + lane]*a1) * inv;
            w.z = (oo[rg2*4+2]*a0 + SF[rg*2048 + (dbi*16 + rg2*4+2)*64 + lane]*a1) * inv;
            w.w = (oo[rg2*4+3]*a0 + SF[rg*2048 + (dbi*16 + rg2*4+3)*64 + lane]*a1) * inv;
            *(float4*)(Og + (size_t)qg*DH + db*32 + rg2*8 + hi*4) = w;
          }
        }
      }
      __syncthreads();
    }
  }
}

extern "C" void kernel_launch(void* const* d_in, const int* in_sizes, int n_in,
                              void* d_out, int out_size, void* d_ws, size_t ws_size,
                              hipStream_t stream) {
  const float* q = (const float*)d_in[0];
  const float* k = (const float*)d_in[1];
  const float* v = (const float*)d_in[2];
  float* out = (float*)d_out;

  const size_t need = 2 * ELEMS * sizeof(unsigned short);   // 32 MB
  if (ws_size >= need){
    unsigned short* kb = (unsigned short*)d_ws;
    unsigned short* vt = kb + ELEMS;
    convkvt<<<3072, 256, 0, stream>>>(k, v, kb, vt);
    attn_fwd_reg<<<256, 512, 0, stream>>>(q, kb, vt, out);
  } else {
    attn_fwd_fb<<<256, 512, 0, stream>>>(q, k, v, out);
  }
}

// Round 28
// 85.270 us; speedup vs baseline: 1.8100x; 1.8100x over previous
//
#include <hip/hip_runtime.h>

#define SQ 2048
#define DH 128
#define KVB 64
#define BHN 32
#define ELEMS ((size_t)BHN * SQ * DH)   // 8388608 per tensor

typedef __bf16 bf16x8 __attribute__((ext_vector_type(8)));
typedef float f32x16 __attribute__((ext_vector_type(16)));
typedef unsigned uint2v __attribute__((ext_vector_type(2)));

__device__ __forceinline__ f32x16 mfma32(bf16x8 a, bf16x8 b, f32x16 c){
  return __builtin_amdgcn_mfma_f32_32x32x16_bf16(a, b, c, 0, 0, 0);
}

#define EXP2 __builtin_amdgcn_exp2f
#define GLD16(g, l) __builtin_amdgcn_global_load_lds( \
    (const __attribute__((address_space(1))) void*)(g), \
    (__attribute__((address_space(3))) void*)(l), 16, 0, 0)
#define VMCNT0 asm volatile("s_waitcnt vmcnt(0)" ::: "memory")
#define VMCNT4 asm volatile("s_waitcnt vmcnt(4)" ::: "memory")
#define VMCNT8 asm volatile("s_waitcnt vmcnt(8)" ::: "memory")
#define BARRIER asm volatile("s_barrier" ::: "memory")

__device__ __forceinline__ unsigned short f2bf(float f){
  unsigned u = __builtin_bit_cast(unsigned, f);
  u += 0x7fffu + ((u >> 16) & 1u);
  return (unsigned short)(u >> 16);
}
__device__ __forceinline__ unsigned packbf(float a, float b){
  return (unsigned)f2bf(a) | ((unsigned)f2bf(b) << 16);
}
// HW packed f32->bf16 pair (distinct "=v" output: no coalescing hazard)
__device__ __forceinline__ unsigned cvtpk(float a, float b){
  unsigned w;
  asm("v_cvt_pk_bf16_f32 %0, %1, %2" : "=v"(w) : "v"(a), "v"(b));
  return w;
}

// HW cross-half exchange: x = {a[0:31], b[0:31]}, y = {a[32:63], b[32:63]}
#if __has_builtin(__builtin_amdgcn_permlane32_swap)
__device__ __forceinline__ void swap32p(unsigned a, unsigned b, unsigned &x, unsigned &y){
  uint2v r = __builtin_amdgcn_permlane32_swap(a, b, false, false);
  x = r[0]; y = r[1];
}
#else
__device__ __forceinline__ void swap32p(unsigned a, unsigned b, unsigned &x, unsigned &y){
  x = a; y = b;
  asm volatile("" : "+v"(x), "+v"(y));   // opaque copies -> distinct live values
  asm("v_permlane32_swap_b32 %0, %1" : "+v"(x), "+v"(y));
}
#endif
__device__ __forceinline__ float halfmax(float t){
  unsigned u = __builtin_bit_cast(unsigned, t), x, y;
  swap32p(u, u, x, y);
  return fmaxf(__builtin_bit_cast(float, x), __builtin_bit_cast(float, y));
}
__device__ __forceinline__ float halfadd(float t){
  unsigned u = __builtin_bit_cast(unsigned, t), x, y;
  swap32p(u, u, x, y);
  return __builtin_bit_cast(float, x) + __builtin_bit_cast(float, y);
}

// emulated version (fallback kernel only)
__device__ __forceinline__ void swap32(unsigned a, unsigned b, bool h, unsigned &x, unsigned &y){
  unsigned sb = __shfl_xor(b, 32);
  unsigned sa = __shfl_xor(a, 32);
  x = h ? sb : a;
  y = h ? b : sa;
}

__device__ __forceinline__ bf16x8 mkfrag(unsigned w0, unsigned w1, unsigned w2, unsigned w3){
  uint4 t; t.x = w0; t.y = w1; t.z = w2; t.w = w3;
  return __builtin_bit_cast(bf16x8, t);
}

// ---- fused preprocess: K fp32->bf16 (blocks 0..1023) + V transpose (1024..3071) ----
__global__ __launch_bounds__(256, 4)
void convkvt(const float* __restrict__ K, const float* __restrict__ V,
             unsigned short* __restrict__ Kb, unsigned short* __restrict__ Vt){
  if (blockIdx.x < 1024){
    const size_t g = (size_t)blockIdx.x * 256 + threadIdx.x;
    #pragma unroll
    for (int i = 0; i < 4; ++i){
      size_t e = (g + (size_t)i * 262144) * 8;
      float4 a = *(const float4*)(K + e);
      float4 b = *(const float4*)(K + e + 4);
      uint4 o;
      o.x = packbf(a.x, a.y); o.y = packbf(a.z, a.w);
      o.z = packbf(b.x, b.y); o.w = packbf(b.z, b.w);
      *(uint4*)(Kb + e) = o;
    }
  } else {
    __shared__ unsigned short T[64][65];
    const int bidx = blockIdx.x - 1024;     // ((bh*32)+kt)*2+dt
    const int dt = bidx & 1;
    const int kt = (bidx >> 1) & 31;
    const int bh = bidx >> 6;
    const float* src = V + (size_t)bh*SQ*DH + (size_t)kt*64*DH + dt*64;
    unsigned short* dst = Vt + (size_t)bh*DH*SQ + (size_t)dt*64*SQ + kt*64;
    const int t = threadIdx.x;
    const int c4 = (t & 15) * 4;
    const int r0 = t >> 4;
    #pragma unroll
    for (int i = 0; i < 4; ++i){
      int r = r0 + i*16;
      float4 f = *(const float4*)(src + (size_t)r*DH + c4);
      T[r][c4+0] = f2bf(f.x); T[r][c4+1] = f2bf(f.y);
      T[r][c4+2] = f2bf(f.z); T[r][c4+3] = f2bf(f.w);
    }
    __syncthreads();
    #pragma unroll
    for (int i = 0; i < 4; ++i){
      int d = r0 + i*16;
      ushort4 w;
      w.x = T[c4+0][d]; w.y = T[c4+1][d]; w.z = T[c4+2][d]; w.w = T[c4+3][d];
      *(ushort4*)(dst + (size_t)d*SQ + c4) = w;
    }
  }
}

// ---- main kernel: 4-buffer ring, 3-deep prefetch, counted vmcnt + raw barrier ----
__global__ __launch_bounds__(512, 2)
void attn_fwd_gl(const float* __restrict__ Q,
                 const unsigned short* __restrict__ Kbg,
                 const unsigned short* __restrict__ Vtg,
                 float* __restrict__ O)
{
  __shared__ __align__(16) unsigned char smem[131072];
  float* SF = (float*)smem;

  const int tid  = threadIdx.x;
  const int lane = tid & 63;
  const int wid  = tid >> 6;
  const int rg   = wid & 3;
  const int par  = wid >> 2;
  const int col  = lane & 31;
  const int hi   = lane >> 5;

  const int b   = blockIdx.x;
  const int xcd = b & 7;
  const int seq = b >> 3;
  const int bh4 = seq & 3;
  const int j   = seq >> 2;
  const int bh  = xcd + 8*bh4;

  const size_t base = (size_t)bh * SQ * DH;
  const float* Qg = Q + base;
  const unsigned short* Kb = Kbg + base;
  const unsigned short* Vt = Vtg + base;     // [128][2048]
  float* Og = O + base;

  const float SC = 0.08838834764831845f * 1.4426950408889634f;

  // staging addresses: LDS dest linear, swizzle on the GLOBAL source (involution)
  const unsigned short* ksrc[2];
  const unsigned short* vsrc[2];
  int kdst[2], vdst[2];
  #pragma unroll
  for (int i = 0; i < 2; ++i){
    int c = i*512 + tid;
    int r = c >> 4, dc = c & 15;
    ksrc[i] = Kb + (size_t)r*DH + ((dc ^ (r & 7)) * 8);
    kdst[i] = c * 16;
    int d = c >> 3, f = c & 7;
    vsrc[i] = Vt + (size_t)d*SQ + ((f ^ ((d >> 1) & 7)) * 8);
    vdst[i] = 16384 + c * 16;
  }

  auto LOADT = [&](int kvb, int bsel){
    const int bboff = bsel * 32768;
    #pragma unroll
    for (int i = 0; i < 2; ++i){
      GLD16(ksrc[i] + (size_t)kvb * DH, &smem[bboff + kdst[i]]);
      GLD16(vsrc[i] + kvb,              &smem[bboff + vdst[i]]);
    }
  };

  #pragma unroll 1
  for (int ph = 0; ph < 2; ++ph){
    const int qt = ph ? j : (15 - j);
    const int nt = 2*qt + 2;          // nt >= 2
    const int Q0 = qt*128 + rg*32;
    const int qg = Q0 + col;

    // Q fragments, softmax scale folded in
    bf16x8 qf[8];
    #pragma unroll
    for (int dc = 0; dc < 8; ++dc){
      const float* src = Qg + (size_t)qg*DH + dc*16 + hi*8;
      float4 f0 = *(const float4*)(src);
      float4 f1 = *(const float4*)(src + 4);
      uint4 tq;
      tq.x = packbf(f0.x*SC, f0.y*SC); tq.y = packbf(f0.z*SC, f0.w*SC);
      tq.z = packbf(f1.x*SC, f1.y*SC); tq.w = packbf(f1.z*SC, f1.w*SC);
      qf[dc] = __builtin_bit_cast(bf16x8, tq);
    }

    f32x16 o0 = {}, o1 = {}, o2 = {}, o3 = {};
    float m = -1e30f, lsum = 0.f;

    // prologue: fill up to 3 ring slots, wait for tile 0 only
    LOADT(0, 0);
    if (nt > 1) LOADT(KVB, 1);
    if (nt > 2) LOADT(2*KVB, 2);
    if (nt > 2){ VMCNT8; } else { VMCNT4; }
    BARRIER;

    #pragma unroll 1
    for (int t = 0; t < nt; ++t){
      const int kvb = t * KVB;
      const int bboff = (t & 3) * 32768;
      const int myk = kvb + par*32;

      if (t + 3 < nt) LOADT(kvb + 3*KVB, (t + 3) & 3);

      if (myk <= Q0 + 31){
        f32x16 s0 = {};
        const int krow = par*32 + col;
        #pragma unroll
        for (int dc = 0; dc < 8; ++dc){
          uint4 rk = *(const uint4*)&smem[bboff + krow*256 + ((dc*32 + hi*16) ^ ((krow & 7) << 4))];
          s0 = mfma32(__builtin_bit_cast(bf16x8, rk), qf[dc], s0);
        }

        if (myk + 31 > Q0){
          #pragma unroll
          for (int r = 0; r < 16; ++r){
            int kl = (r & 3) + 8*(r >> 2) + 4*hi;
            if (myk + kl > qg) s0[r] = -1e30f;
          }
        }

        // tree max-reduce (depth 4) + HW cross-half max
        float p0 = fmaxf(s0[0],  s0[1]),  p1 = fmaxf(s0[2],  s0[3]);
        float p2 = fmaxf(s0[4],  s0[5]),  p3 = fmaxf(s0[6],  s0[7]);
        float p4 = fmaxf(s0[8],  s0[9]),  p5 = fmaxf(s0[10], s0[11]);
        float p6 = fmaxf(s0[12], s0[13]), p7 = fmaxf(s0[14], s0[15]);
        float q0v = fmaxf(p0, p1), q1v = fmaxf(p2, p3);
        float q2v = fmaxf(p4, p5), q3v = fmaxf(p6, p7);
        float tmax = halfmax(fmaxf(fmaxf(q0v, q1v), fmaxf(q2v, q3v)));
        if (!__all(tmax <= m + 8.0f)){      // T13 defer-max
          float mnew  = fmaxf(m, tmax);
          float alpha = EXP2(m - mnew);
          m = mnew;
          lsum *= alpha;
          o0 *= alpha; o1 *= alpha; o2 *= alpha; o3 *= alpha;
        }

        // exp2 + tree sum (depth 4) + HW packed bf16 conversion
        float e0  = EXP2(s0[0]  - m), e1  = EXP2(s0[1]  - m);
        float e2  = EXP2(s0[2]  - m), e3  = EXP2(s0[3]  - m);
        float e4  = EXP2(s0[4]  - m), e5  = EXP2(s0[5]  - m);
        float e6  = EXP2(s0[6]  - m), e7  = EXP2(s0[7]  - m);
        float e8  = EXP2(s0[8]  - m), e9  = EXP2(s0[9]  - m);
        float e10 = EXP2(s0[10] - m), e11 = EXP2(s0[11] - m);
        float e12 = EXP2(s0[12] - m), e13 = EXP2(s0[13] - m);
        float e14 = EXP2(s0[14] - m), e15 = EXP2(s0[15] - m);
        lsum += (((e0+e1)+(e2+e3)) + ((e4+e5)+(e6+e7)))
              + (((e8+e9)+(e10+e11)) + ((e12+e13)+(e14+e15)));

        unsigned ua0 = cvtpk(e0,  e1),  ua1 = cvtpk(e2,  e3);
        unsigned ua2 = cvtpk(e4,  e5),  ua3 = cvtpk(e6,  e7);
        unsigned ua4 = cvtpk(e8,  e9),  ua5 = cvtpk(e10, e11);
        unsigned ua6 = cvtpk(e12, e13), ua7 = cvtpk(e14, e15);
        unsigned w0, w1, w2, w3;
        bf16x8 pf[2];
        swap32p(ua0, ua2, w0, w2); swap32p(ua1, ua3, w1, w3); pf[0] = mkfrag(w0,w1,w2,w3);
        swap32p(ua4, ua6, w0, w2); swap32p(ua5, ua7, w1, w3); pf[1] = mkfrag(w0,w1,w2,w3);

        #pragma unroll
        for (int cc = 0; cc < 2; ++cc){
          #pragma unroll
          for (int db = 0; db < 4; ++db){
            int rowd = db*32 + col;
            uint4 rv = *(const uint4*)&smem[bboff + 16384 + rowd*128 + ((par*64 + cc*32 + hi*16) ^ (((rowd >> 1) & 7) << 4))];
            f32x16& oo = (db==0)?o0:(db==1)?o1:(db==2)?o2:o3;
            oo = mfma32(__builtin_bit_cast(bf16x8, rv), pf[cc], oo);
          }
        }
      }

      if (t + 1 < nt){
        const int rem = nt - 2 - t;
        if (rem >= 2){ VMCNT8; } else if (rem == 1){ VMCNT4; } else { VMCNT0; }
      }
      BARRIER;
    }

    // ---- epilogue: combine hi-halves, then parity merge via LDS ----
    lsum = halfadd(lsum);

    float a0 = 1.f, a1 = 0.f, inv = 0.f;
    #pragma unroll 1
    for (int round = 0; round < 2; ++round){
      const f32x16& pa = round ? o2 : o0;
      const f32x16& pb = round ? o3 : o1;
      if (par == 1){
        #pragma unroll
        for (int i2 = 0; i2 < 16; ++i2){
          SF[rg*2048 + i2*64 + lane]      = pa[i2];
          SF[rg*2048 + (16+i2)*64 + lane] = pb[i2];
        }
        if (round == 0){
          SF[8192 + rg*64 + lane] = m;
          SF[8448 + rg*64 + lane] = lsum;
        }
      }
      __syncthreads();
      if (par == 0){
        if (round == 0){
          float m1 = SF[8192 + rg*64 + lane];
          float l1 = SF[8448 + rg*64 + lane];
          float ms = fmaxf(m, m1);
          a0 = EXP2(m - ms);
          a1 = EXP2(m1 - ms);
          float ls = lsum*a0 + l1*a1;
          inv = 1.0f / ls;
        }
        #pragma unroll
        for (int dbi = 0; dbi < 2; ++dbi){
          const f32x16& oo = round ? (dbi ? o3 : o2) : (dbi ? o1 : o0);
          const int db = round*2 + dbi;
          #pragma unroll
          for (int rg2 = 0; rg2 < 4; ++rg2){
            float4 w;
            w.x = (oo[rg2*4+0]*a0 + SF[rg*2048 + (dbi*16 + rg2*4+0)*64 + lane]*a1) * inv;
            w.y = (oo[rg2*4+1]*a0 + SF[rg*2048 + (dbi*16 + rg2*4+1)*64 + lane]*a1) * inv;
            w.z = (oo[rg2*4+2]*a0 + SF[rg*2048 + (dbi*16 + rg2*4+2)*64 + lane]*a1) * inv;
            w.w = (oo[rg2*4+3]*a0 + SF[rg*2048 + (dbi*16 + rg2*4+3)*64 + lane]*a1) * inv;
            *(float4*)(Og + (size_t)qg*DH + db*32 + rg2*8 + hi*4) = w;
          }
        }
      }
      __syncthreads();
    }
  }
}

// ---- fallback (ws too small): reg-staged fp32 path (R18-verified) ----
__global__ __launch_bounds__(512, 2)
void attn_fwd_fb(const float* __restrict__ Q,
                 const float* __restrict__ Kf,
                 const float* __restrict__ Vf,
                 float* __restrict__ O)
{
  __shared__ __align__(16) unsigned char smem[65536];
  float* SF = (float*)smem;
  const int tid  = threadIdx.x;
  const int lane = tid & 63;
  const int wid  = tid >> 6;
  const int rg   = wid & 3;
  const int par  = wid >> 2;
  const int col  = lane & 31;
  const int hi   = lane >> 5;
  const int i4   = lane & 3;
  const int d0   = (lane >> 2)*8;
  const int b   = blockIdx.x;
  const int xcd = b & 7;
  const int seq = b >> 3;
  const int bh4 = seq & 3;
  const int j   = seq >> 2;
  const int bh  = xcd + 8*bh4;
  const size_t base = (size_t)bh * SQ * DH;
  const float* Qg = Q + base;
  const float* Kg = Kf + base;
  const float* Vg = Vf + base;
  float* Og = O + base;
  const float SC = 0.08838834764831845f * 1.4426950408889634f;
  float4 kr[4], vr[4];
  auto LOADT = [&](int kvb){
    #pragma unroll
    for (int i2 = 0; i2 < 2; ++i2){
      int c = i2*512 + tid, r = c >> 4, dc = c & 15;
      const float* src = Kg + (size_t)(kvb + r)*DH + dc*8;
      kr[2*i2]   = *(const float4*)(src);
      kr[2*i2+1] = *(const float4*)(src + 4);
    }
    #pragma unroll
    for (int it = 0; it < 2; ++it){
      int row = wid*8 + it*4 + i4;
      const float* src = Vg + (size_t)(kvb + row)*DH + d0;
      vr[2*it]   = *(const float4*)(src);
      vr[2*it+1] = *(const float4*)(src + 4);
    }
  };
  auto STORET = [&](int bsel){
    const int bboff = bsel * 32768;
    #pragma unroll
    for (int i2 = 0; i2 < 2; ++i2){
      int c = i2*512 + tid, r = c >> 4, dc = c & 15;
      uint4 kv;
      kv.x = packbf(kr[2*i2].x,   kr[2*i2].y);
      kv.y = packbf(kr[2*i2].z,   kr[2*i2].w);
      kv.z = packbf(kr[2*i2+1].x, kr[2*i2+1].y);
      kv.w = packbf(kr[2*i2+1].z, kr[2*i2+1].w);
      *(uint4*)&smem[bboff + r*256 + ((dc*16) ^ ((r & 7) << 4))] = kv;
    }
    #pragma unroll
    for (int it = 0; it < 2; ++it){
      int r0 = wid*8 + it*4;
      unsigned M0 = packbf(vr[2*it].x,   vr[2*it].y);
      unsigned M1 = packbf(vr[2*it].z,   vr[2*it].w);
      unsigned M2 = packbf(vr[2*it+1].x, vr[2*it+1].y);
      unsigned M3 = packbf(vr[2*it+1].z, vr[2*it+1].w);
      unsigned t0=__shfl_xor(M1,1), t1=__shfl_xor(M0,1), t2=__shfl_xor(M3,1), t3=__shfl_xor(M2,1);
      bool ob1 = i4 & 1;
      unsigned N0 = ob1 ? t0 : M0;
      unsigned N1 = ob1 ? M1 : t1;
      unsigned N2 = ob1 ? t2 : M2;
      unsigned N3 = ob1 ? M3 : t3;
      unsigned u0s=__shfl_xor(N2,2), u1s=__shfl_xor(N3,2), u2s=__shfl_xor(N0,2), u3s=__shfl_xor(N1,2);
      bool ob2 = i4 & 2;
      unsigned F0 = ob2 ? u0s : N0;
      unsigned F1 = ob2 ? u1s : N1;
      unsigned F2 = ob2 ? N2 : u2s;
      unsigned F3 = ob2 ? N3 : u3s;
      int d = d0 + 2*i4;
      unsigned lo0 = (F0 & 0xffffu) | (F1 << 16);
      unsigned lo1 = (F2 & 0xffffu) | (F3 << 16);
      unsigned hi0 = (F0 >> 16) | (F1 & 0xffff0000u);
      unsigned hi1 = (F2 >> 16) | (F3 & 0xffff0000u);
      int cb = r0*2;
      int sA = ((d >> 1) & 7) << 4;
      *(uint2*)&smem[bboff + 16384 + d*128     + (cb ^ sA)] = make_uint2(lo0, lo1);
      *(uint2*)&smem[bboff + 16384 + (d+1)*128 + (cb ^ sA)] = make_uint2(hi0, hi1);
    }
  };
  #pragma unroll 1
  for (int ph = 0; ph < 2; ++ph){
    const int qt = ph ? j : (15 - j);
    const int nt = 2*qt + 2;
    const int Q0 = qt*128 + rg*32;
    const int qg = Q0 + col;
    bf16x8 qf[8];
    #pragma unroll
    for (int dc = 0; dc < 8; ++dc){
      const float* src = Qg + (size_t)qg*DH + dc*16 + hi*8;
      float4 f0 = *(const float4*)(src);
      float4 f1 = *(const float4*)(src + 4);
      uint4 tq;
      tq.x = packbf(f0.x*SC, f0.y*SC); tq.y = packbf(f0.z*SC, f0.w*SC);
      tq.z = packbf(f1.x*SC, f1.y*SC); tq.w = packbf(f1.z*SC, f1.w*SC);
      qf[dc] = __builtin_bit_cast(bf16x8, tq);
    }
    f32x16 o0 = {}, o1 = {}, o2 = {}, o3 = {};
    float m = -1e30f, lsum = 0.f;
    LOADT(0);
    STORET(0);
    __syncthreads();
    #pragma unroll 1
    for (int t = 0; t < nt; ++t){
      const int kvb = t * KVB;
      const int bboff = (t & 1) * 32768;
      const int myk = kvb + par*32;
      if (t + 1 < nt) LOADT(kvb + KVB);
      if (myk <= Q0 + 31){
        f32x16 s0 = {};
        const int krow = par*32 + col;
        #pragma unroll
        for (int dc = 0; dc < 8; ++dc){
          uint4 rk = *(const uint4*)&smem[bboff + krow*256 + ((dc*32 + hi*16) ^ ((krow & 7) << 4))];
          s0 = mfma32(__builtin_bit_cast(bf16x8, rk), qf[dc], s0);
        }
        if (myk + 31 > Q0){
          #pragma unroll
          for (int r = 0; r < 16; ++r){
            int kl = (r & 3) + 8*(r >> 2) + 4*hi;
            if (myk + kl > qg) s0[r] = -1e30f;
          }
        }
        float tmax = -1e30f;
        #pragma unroll
        for (int r = 0; r < 16; ++r) tmax = fmaxf(tmax, s0[r]);
        tmax = fmaxf(tmax, __shfl_xor(tmax, 32));
        if (!__all(tmax <= m + 8.0f)){
          float mnew  = fmaxf(m, tmax);
          float alpha = EXP2(m - mnew);
          m = mnew;
          lsum *= alpha;
          o0 *= alpha; o1 *= alpha; o2 *= alpha; o3 *= alpha;
        }
        float ps = 0.f;
        #pragma unroll
        for (int r = 0; r < 16; ++r){ float e = EXP2(s0[r] - m); s0[r] = e; ps += e; }
        lsum += ps;
        unsigned ua0 = packbf(s0[0],  s0[1]),  ua1 = packbf(s0[2],  s0[3]);
        unsigned ua2 = packbf(s0[4],  s0[5]),  ua3 = packbf(s0[6],  s0[7]);
        unsigned ua4 = packbf(s0[8],  s0[9]),  ua5 = packbf(s0[10], s0[11]);
        unsigned ua6 = packbf(s0[12], s0[13]), ua7 = packbf(s0[14], s0[15]);
        bool h = (bool)hi;
        unsigned w0, w1, w2, w3;
        bf16x8 pf[2];
        swap32(ua0, ua2, h, w0, w2); swap32(ua1, ua3, h, w1, w3); pf[0] = mkfrag(w0,w1,w2,w3);
        swap32(ua4, ua6, h, w0, w2); swap32(ua5, ua7, h, w1, w3); pf[1] = mkfrag(w0,w1,w2,w3);
        #pragma unroll
        for (int cc = 0; cc < 2; ++cc){
          #pragma unroll
          for (int db = 0; db < 4; ++db){
            int rowd = db*32 + col;
            uint4 rv = *(const uint4*)&smem[bboff + 16384 + rowd*128 + ((par*64 + cc*32 + hi*16) ^ (((rowd >> 1) & 7) << 4))];
            f32x16& oo = (db==0)?o0:(db==1)?o1:(db==2)?o2:o3;
            oo = mfma32(__builtin_bit_cast(bf16x8, rv), pf[cc], oo);
          }
        }
      }
      if (t + 1 < nt) STORET((t + 1) & 1);
      __syncthreads();
    }
    lsum += __shfl_xor(lsum, 32);
    float a0 = 1.f, a1 = 0.f, inv = 0.f;
    #pragma unroll 1
    for (int round = 0; round < 2; ++round){
      const f32x16& pa = round ? o2 : o0;
      const f32x16& pb = round ? o3 : o1;
      if (par == 1){
        #pragma unroll
        for (int i2 = 0; i2 < 16; ++i2){
          SF[rg*2048 + i2*64 + lane]      = pa[i2];
          SF[rg*2048 + (16+i2)*64 + lane] = pb[i2];
        }
        if (round == 0){
          SF[8192 + rg*64 + lane] = m;
          SF[8448 + rg*64 + lane] = lsum;
        }
      }
      __syncthreads();
      if (par == 0){
        if (round == 0){
          float m1 = SF[8192 + rg*64 + lane];
          float l1 = SF[8448 + rg*64 + lane];
          float ms = fmaxf(m, m1);
          a0 = EXP2(m - ms);
          a1 = EXP2(m1 - ms);
          float ls = lsum*a0 + l1*a1;
          inv = 1.0f / ls;
        }
        #pragma unroll
        for (int dbi = 0; dbi < 2; ++dbi){
          const f32x16& oo = round ? (dbi ? o3 : o2) : (dbi ? o1 : o0);
          const int db = round*2 + dbi;
          #pragma unroll
          for (int rg2 = 0; rg2 < 4; ++rg2){
            float4 w;
            w.x = (oo[rg2*4+0]*a0 + SF[rg*2048 + (dbi*16 + rg2*4+0)*64 + lane]*a1) * inv;
            w.y = (oo[rg2*4+1]*a0 + SF[rg*2048 + (dbi*16 + rg2*4+1)*64 + lane]*a1) * inv;
            w.z = (oo[rg2*4+2]*a0 + SF[rg*2048 + (dbi*16 + rg2*4+2)*64 + lane]*a1) * inv;
            w.w = (oo[rg2*4+3]*a0 + SF[rg*2048 + (dbi*16 + rg2*4+3)*64 + lane]*a1) * inv;
            *(float4*)(Og + (size_t)qg*DH + db*32 + rg2*8 + hi*4) = w;
          }
        }
      }
      __syncthreads();
    }
  }
}

extern "C" void kernel_launch(void* const* d_in, const int* in_sizes, int n_in,
                              void* d_out, int out_size, void* d_ws, size_t ws_size,
                              hipStream_t stream) {
  const float* q = (const float*)d_in[0];
  const float* k = (const float*)d_in[1];
  const float* v = (const float*)d_in[2];
  float* out = (float*)d_out;

  const size_t need = 2 * ELEMS * sizeof(unsigned short);   // 32 MB
  if (ws_size >= need){
    unsigned short* kb = (unsigned short*)d_ws;
    unsigned short* vt = kb + ELEMS;
    convkvt<<<3072, 256, 0, stream>>>(k, v, kb, vt);
    attn_fwd_gl<<<256, 512, 0, stream>>>(q, kb, vt, out);
  } else {
    attn_fwd_fb<<<256, 512, 0, stream>>>(q, k, v, out);
  }
}